// Round 6
// baseline (399.908 us; speedup 1.0000x reference)
//
#include <hip/hip_runtime.h>
#include <math.h>

#define HW   4096
#define CINP 512
#define LCH  64

typedef short bf8 __attribute__((ext_vector_type(8)));   // 8 bf16 = 4 VGPRs
typedef float f4  __attribute__((ext_vector_type(4)));   // MFMA C/D frag
typedef unsigned int u32x2 __attribute__((ext_vector_type(2)));

__device__ __forceinline__ unsigned short f2bf(float x) {
    union { float f; unsigned int u; } v; v.f = x;
    return (unsigned short)((v.u + 0x7fffu + ((v.u >> 16) & 1u)) >> 16);
}
__device__ __forceinline__ bf8 ldbf8(const unsigned short* p) {
    uint4 u = *(const uint4*)p;
    return __builtin_bit_cast(bf8, u);
}
// pack two f32 -> two bf16 (RNE), dst.lo = a, dst.hi = b
__device__ __forceinline__ unsigned int cvtpk(float a, float b) {
    unsigned int r;
    asm volatile("v_cvt_pk_bf16_f32 %0, %1, %2" : "=v"(r) : "v"(a), "v"(b));
    return r;
}

// -------------------------------------------------------------------------
// precast: weights (+gain) and concepts to bf16, concepts also transposed.
// WB[192][512] = [wt;wp;wg]*gain   WO[512][64]   CK[256][64]   CV[64][256]
// -------------------------------------------------------------------------
__global__ __launch_bounds__(256) void precast(
    const float* __restrict__ wt, const float* __restrict__ wp,
    const float* __restrict__ wg, const float* __restrict__ wo,
    const float* __restrict__ conc,
    unsigned short* __restrict__ WB, unsigned short* __restrict__ WO,
    unsigned short* __restrict__ CK, unsigned short* __restrict__ CV)
{
    const float gain = 0.04419417382415922f;  // 1/sqrt(512)
    int id = blockIdx.x * 256 + threadIdx.x;
    if (id < 98304) {
        int o = id >> 9, k = id & 511;
        const float* w = (o < 64) ? wt : (o < 128) ? wp : wg;
        WB[id] = f2bf(w[(o & 63) * 512 + k] * gain);
    } else if (id < 131072) {
        int j = id - 98304;
        WO[j] = f2bf(wo[j]);
    } else if (id < 147456) {
        int j = id - 131072;
        CK[j] = f2bf(conc[j]);
    } else if (id < 163840) {
        int j = id - 147456;
        int l = j >> 8, m = j & 255;
        CV[j] = f2bf(conc[m * 64 + l]);
    }
}

// -------------------------------------------------------------------------
// cast_transpose: f fp32 [b][512][4096] -> XT bf16 [b][4096][512]
// -------------------------------------------------------------------------
__global__ __launch_bounds__(256) void cast_transpose(const float* __restrict__ x,
                                                      unsigned short* __restrict__ XT)
{
    __shared__ unsigned short Lb[64][72];   // [n][c]
    const int t  = threadIdx.x;
    const int n0 = blockIdx.x * 64, c0 = blockIdx.y * 64, b = blockIdx.z;
    const float* xb = x + ((size_t)b * CINP + c0) * HW + n0;
    const int cc = t >> 4, n4 = (t & 15) * 4;
    #pragma unroll
    for (int i = 0; i < 4; i++) {
        int c = cc + i * 16;
        float4 v = *(const float4*)(xb + (size_t)c * HW + n4);
        Lb[n4 + 0][c] = f2bf(v.x);
        Lb[n4 + 1][c] = f2bf(v.y);
        Lb[n4 + 2][c] = f2bf(v.z);
        Lb[n4 + 3][c] = f2bf(v.w);
    }
    __syncthreads();
    const int n = t & 63, cb0 = t >> 6;
    unsigned short* orow = XT + ((size_t)b * HW + n0 + n) * CINP + c0;
    #pragma unroll
    for (int i = 0; i < 2; i++) {
        int cb = cb0 + i * 4;
        *(uint4*)(orow + cb * 8) = *(const uint4*)&Lb[n][cb * 8];
    }
}

// -------------------------------------------------------------------------
// lat_transpose: A bf16 flat [b][4096][64] viewed as lat[b][64][4096]
// (raw reinterpret, the torch .view) -> LT[b][4096][64] with LT[b][s][c] =
// lat[b][c][s] = Aflat[b*262144 + c*4096 + s].  64x64 LDS tile.
// -------------------------------------------------------------------------
__global__ __launch_bounds__(256) void lat_transpose(const unsigned short* __restrict__ A,
                                                     unsigned short* __restrict__ LT)
{
    __shared__ unsigned short Ls[64][72];
    const int t = threadIdx.x, s0 = blockIdx.x * 64, b = blockIdx.y;
    const unsigned short* ab = A + (size_t)b * LCH * HW;
    #pragma unroll
    for (int it = 0; it < 2; it++) {
        int c = (t >> 3) + it * 32, s8 = (t & 7) * 8;
        union { uint4 u; unsigned short s[8]; } v;
        v.u = *(const uint4*)(ab + (size_t)c * HW + s0 + s8);
        #pragma unroll
        for (int i = 0; i < 8; i++) Ls[s8 + i][c] = v.s[i];
    }
    __syncthreads();
    unsigned short* ob = LT + ((size_t)b * HW + s0) * LCH;
    #pragma unroll
    for (int it = 0; it < 2; it++) {
        int s = (t >> 3) + it * 32, c8 = (t & 7);
        *(uint4*)(ob + (size_t)s * LCH + c8 * 8) = *(const uint4*)&Ls[s][c8 * 8];
    }
}

// -------------------------------------------------------------------------
// qkv_gemm<NRT>: barrier-free, LDS-free; A (weights) and B (XT rows) frags
// direct from global. NRT=12: Q -> XT cols [0,64), K -> [64,128), V -> VL.
// NRT=4: enc -> XT cols [0,64).
// -------------------------------------------------------------------------
template <int NRT>
__global__ __launch_bounds__(256) void qkv_gemm(unsigned short* XT,
                                                const unsigned short* __restrict__ WB,
                                                unsigned short* __restrict__ VL)
{
    const int t = threadIdx.x;
    const int wave = t >> 6, lane = t & 63, quad = lane >> 4, lidx = lane & 15;
    const int b = blockIdx.y;
    const int ncol = blockIdx.x * 64 + wave * 16 + lidx;
    unsigned short* xrow = XT + ((size_t)b * HW + ncol) * CINP;

    f4 acc[NRT];
    #pragma unroll
    for (int r = 0; r < NRT; r++) acc[r] = (f4){0.f, 0.f, 0.f, 0.f};

    for (int kk = 0; kk < 16; kk++) {
        const int k0 = kk * 32 + quad * 8;
        bf8 bq = ldbf8(xrow + k0);
        #pragma unroll
        for (int rt = 0; rt < NRT; rt++) {
            bf8 aw = ldbf8(WB + (size_t)(rt * 16 + lidx) * CINP + k0);
            acc[rt] = __builtin_amdgcn_mfma_f32_16x16x32_bf16(aw, bq, acc[rt], 0, 0, 0);
        }
    }

    #pragma unroll
    for (int rt = 0; rt < NRT; rt++) {
        if (rt < 8) {  // Q (rt<4) and K (rt<8): n-major, in place in XT
            union { unsigned short s[4]; uint2 u; } pk;
            #pragma unroll
            for (int r = 0; r < 4; r++) pk.s[r] = f2bf(acc[rt][r]);
            int off = (rt < 4) ? (rt * 16 + quad * 4) : (64 + (rt - 4) * 16 + quad * 4);
            *(uint2*)(xrow + off) = pk.u;
        } else {       // V: l-major
            #pragma unroll
            for (int r = 0; r < 4; r++) {
                int l = (rt - 8) * 16 + quad * 4 + r;
                VL[((size_t)b * LCH + l) * HW + ncol] = f2bf(acc[rt][r]);
            }
        }
    }
}

// -------------------------------------------------------------------------
// flash: split-Q, cooperative-LDS-staging, max-free-softmax MFMA attention.
// Block = 2 waves x 32 queries = 64 queries (128 threads); grid 64x8 = 512
// blocks = 2 INDEPENDENT blocks/CU (no shared barrier -> one block's DS
// burst overlaps the other's MFMA/exp phase).
//
// DS diet (round-4 counters showed ~75% DS-pipe busy):
//  * K staged [32][72] padded (144 B rows, 16B-aligned; kf-read banks
//    4*(lidx+chunk) mod 32 -> uniform 2-way). V [64][40] padded (80 B rows;
//    banks 20l+4q mod 32 -> uniform). Both layouts proven in round 4.
//  * P never touches LDS: after swapped QK^T (S = mfma(K,Q) -> D[key][query]),
//    per-lane P is repacked to the PV A-operand layout IN REGISTERS via
//    v_cvt_pk_bf16_f32 + permlane32_swap/permlane16_swap BUILTINS
//    (compiler inserts the required lane-crossing hazard waits -- the raw
//    inline-asm version of this repack silently corrupted data, round 5):
//       {X,Z} = pl16(pl32(A,C)) = [A0,A2,C0,C2],[A1,A3,C1,C3]; same for B,D.
// Out: bf16 [b][4096][64] (n-major).
// -------------------------------------------------------------------------
__global__ __launch_bounds__(128) void flash(
    const unsigned short* Qb, size_t qbat,
    const unsigned short* Kb, size_t krow, size_t kbat,
    const unsigned short* Vb, size_t vrow, size_t vbat,
    unsigned short* __restrict__ Aout, int nkeys)
{
    __shared__ __align__(16) unsigned short Ks[2][32][72];  // [buf][key][ch]
    __shared__ __align__(16) unsigned short Vs[2][64][40];  // [buf][l][key]

    const int t = threadIdx.x;          // 0..127
    const int wave = t >> 6, lane = t & 63, quad = lane >> 4, lidx = lane & 15;
    const int b = blockIdx.y, q0 = blockIdx.x * 64 + wave * 32;

    const unsigned short* qp = Qb + (size_t)b * qbat;
    const unsigned short* kp = Kb + (size_t)b * kbat;
    const unsigned short* vp = Vb + (size_t)b * vbat;

    // staging: 2 K chunks + 2 V chunks (16B each) per thread per tile
    const int kkey0 = t >> 3, kch = t & 7;          // K: key t>>3, chunk t&7
    const int kkey1 = kkey0 + 16;
    const int vr0 = t >> 2, vch = t & 3;            // V: row t>>2, chunk t&3
    const int vr1 = vr0 + 32;

    // Q fragments (B-operand of swapped QK): Q[query qb*16+lidx][ch kh*32+quad*8]
    bf8 qa[2][2];
    #pragma unroll
    for (int qb = 0; qb < 2; qb++)
        #pragma unroll
        for (int kh = 0; kh < 2; kh++)
            qa[qb][kh] = ldbf8(qp + (size_t)(q0 + qb * 16 + lidx) * CINP + kh * 32 + quad * 8);

    f4 O[2][4];
    float Lp[2] = {0.f, 0.f};
    #pragma unroll
    for (int qb = 0; qb < 2; qb++)
        #pragma unroll
        for (int lt = 0; lt < 4; lt++) O[qb][lt] = (f4){0.f, 0.f, 0.f, 0.f};

    const int nt = nkeys >> 5;

    // prologue: stage tile 0 into buf 0
    {
        uint4 k0 = *(const uint4*)(kp + (size_t)kkey0 * krow + kch * 8);
        uint4 k1 = *(const uint4*)(kp + (size_t)kkey1 * krow + kch * 8);
        uint4 v0 = *(const uint4*)(vp + (size_t)vr0 * vrow + vch * 8);
        uint4 v1 = *(const uint4*)(vp + (size_t)vr1 * vrow + vch * 8);
        *(uint4*)&Ks[0][kkey0][kch * 8] = k0;
        *(uint4*)&Ks[0][kkey1][kch * 8] = k1;
        *(uint4*)&Vs[0][vr0][vch * 8] = v0;
        *(uint4*)&Vs[0][vr1][vch * 8] = v1;
    }
    __syncthreads();

    for (int tl = 0; tl < nt; tl++) {
        const int cur = tl & 1;
        const bool pfv = (tl + 1 < nt);
        uint4 kq0, kq1, vq0, vq1;
        if (pfv) {  // issue next-tile global loads early; written after compute
            const int m1 = (tl + 1) * 32;
            kq0 = *(const uint4*)(kp + (size_t)(m1 + kkey0) * krow + kch * 8);
            kq1 = *(const uint4*)(kp + (size_t)(m1 + kkey1) * krow + kch * 8);
            vq0 = *(const uint4*)(vp + (size_t)vr0 * vrow + m1 + vch * 8);
            vq1 = *(const uint4*)(vp + (size_t)vr1 * vrow + m1 + vch * 8);
        }

        // K frags (A-operand): K[key ms*16+lidx][ch kh*32+quad*8]
        bf8 kf[2][2];
        #pragma unroll
        for (int ms = 0; ms < 2; ms++)
            #pragma unroll
            for (int kh = 0; kh < 2; kh++)
                kf[ms][kh] = *(const bf8*)&Ks[cur][ms * 16 + lidx][kh * 32 + quad * 8];

        // S = K . Q^T : D[key quad*4+r (+ms*16)][query lidx (+qb*16)]
        f4 S[2][2];
        #pragma unroll
        for (int qb = 0; qb < 2; qb++)
            #pragma unroll
            for (int ms = 0; ms < 2; ms++) {
                f4 s = (f4){0.f, 0.f, 0.f, 0.f};
                s = __builtin_amdgcn_mfma_f32_16x16x32_bf16(kf[ms][0], qa[qb][0], s, 0, 0, 0);
                s = __builtin_amdgcn_mfma_f32_16x16x32_bf16(kf[ms][1], qa[qb][1], s, 0, 0, 0);
                S[qb][ms] = s;
            }

        // P = exp(S); repack D[key][query] -> A-operand P[query][key] in regs
        bf8 pa[2];
        #pragma unroll
        for (int qb = 0; qb < 2; qb++) {
            float e00 = __expf(S[qb][0][0]), e01 = __expf(S[qb][0][1]);
            float e02 = __expf(S[qb][0][2]), e03 = __expf(S[qb][0][3]);
            float e10 = __expf(S[qb][1][0]), e11 = __expf(S[qb][1][1]);
            float e12 = __expf(S[qb][1][2]), e13 = __expf(S[qb][1][3]);
            Lp[qb] += ((e00 + e01) + (e02 + e03)) + ((e10 + e11) + (e12 + e13));
            unsigned int A = cvtpk(e00, e01), B = cvtpk(e02, e03);
            unsigned int C = cvtpk(e10, e11), D = cvtpk(e12, e13);
            u32x2 ac = __builtin_amdgcn_permlane32_swap(A, C, false, false);
            u32x2 xz = __builtin_amdgcn_permlane16_swap(ac.x, ac.y, false, false);
            u32x2 bd = __builtin_amdgcn_permlane32_swap(B, D, false, false);
            u32x2 yw = __builtin_amdgcn_permlane16_swap(bd.x, bd.y, false, false);
            uint4 pu; pu.x = xz.x; pu.y = yw.x; pu.z = xz.y; pu.w = yw.y;
            pa[qb] = __builtin_bit_cast(bf8, pu);
        }

        // PV: A = P[query][key], B = V[l][key]
        #pragma unroll
        for (int lt = 0; lt < 4; lt++) {
            bf8 vf = *(const bf8*)&Vs[cur][lt * 16 + lidx][quad * 8];
            O[0][lt] = __builtin_amdgcn_mfma_f32_16x16x32_bf16(pa[0], vf, O[0][lt], 0, 0, 0);
            O[1][lt] = __builtin_amdgcn_mfma_f32_16x16x32_bf16(pa[1], vf, O[1][lt], 0, 0, 0);
        }

        if (pfv) {  // write prefetched tile into the other buffer
            *(uint4*)&Ks[cur ^ 1][kkey0][kch * 8] = kq0;
            *(uint4*)&Ks[cur ^ 1][kkey1][kch * 8] = kq1;
            *(uint4*)&Vs[cur ^ 1][vr0][vch * 8] = vq0;
            *(uint4*)&Vs[cur ^ 1][vr1][vch * 8] = vq1;
        }
        __syncthreads();
    }

    // ---- normalize & write: L[query] lives at lane lidx=query (cross-quad sum) ----
    float inv[2];
    #pragma unroll
    for (int qb = 0; qb < 2; qb++) {
        float s = Lp[qb];
        s += __shfl_xor(s, 16);
        s += __shfl_xor(s, 32);
        inv[qb] = 1.f / s;
    }
    #pragma unroll
    for (int qb = 0; qb < 2; qb++)
        #pragma unroll
        for (int r = 0; r < 4; r++) {
            float iv = __shfl(inv[qb], quad * 4 + r);  // query qb*16+quad*4+r
            size_t n = (size_t)b * HW + q0 + qb * 16 + quad * 4 + r;
            #pragma unroll
            for (int lt = 0; lt < 4; lt++)
                Aout[n * LCH + lt * 16 + lidx] = f2bf(O[qb][lt][r] * iv);
        }
}

// -------------------------------------------------------------------------
// conv_o: out[b,o,s] = gamma/8 * sum_c WO[o,c]*LT[s,c] + res[b,o,s]
// LT: bf16 [b][4096][64] with LT[s][c] = lat[c][s] (lat_transpose output).
// Optionally emits ST bf16 [b][s][512] (transposed sa_out for stage-2).
// -------------------------------------------------------------------------
__global__ __launch_bounds__(256) void conv_o(const unsigned short* __restrict__ LT,
                                              const unsigned short* __restrict__ WO,
                                              const float* __restrict__ res,
                                              const float* __restrict__ gamma_p,
                                              float* __restrict__ out,
                                              unsigned short* ST)
{
    const int t = threadIdx.x;
    const int wave = t >> 6, lane = t & 63, quad = lane >> 4, lidx = lane & 15;
    const int b = blockIdx.z, o0 = blockIdx.y * 64;
    const int scol = blockIdx.x * 64 + wave * 16 + lidx;
    const unsigned short* arow = LT + ((size_t)b * HW + scol) * LCH;

    f4 acc[4];
    #pragma unroll
    for (int ot = 0; ot < 4; ot++) acc[ot] = (f4){0.f, 0.f, 0.f, 0.f};

    #pragma unroll
    for (int kh = 0; kh < 2; kh++) {
        bf8 bq = ldbf8(arow + kh * 32 + quad * 8);
        #pragma unroll
        for (int ot = 0; ot < 4; ot++) {
            bf8 af = ldbf8(WO + (size_t)(o0 + ot * 16 + lidx) * LCH + kh * 32 + quad * 8);
            acc[ot] = __builtin_amdgcn_mfma_f32_16x16x32_bf16(af, bq, acc[ot], 0, 0, 0);
        }
    }

    const float scale = gamma_p[0] * 0.125f;  // gamma * 1/sqrt(64)
    #pragma unroll
    for (int ot = 0; ot < 4; ot++) {
        float v[4];
        #pragma unroll
        for (int r = 0; r < 4; r++) {
            size_t idx = ((size_t)b * CINP + o0 + ot * 16 + quad * 4 + r) * HW + scol;
            v[r] = fmaf(scale, acc[ot][r], res[idx]);
            out[idx] = v[r];
        }
        if (ST) {
            union { unsigned short s[4]; uint2 u; } pk;
            #pragma unroll
            for (int r = 0; r < 4; r++) pk.s[r] = f2bf(v[r]);
            *(uint2*)(ST + ((size_t)b * HW + scol) * CINP + o0 + ot * 16 + quad * 4) = pk.u;
        }
    }
}

// -------------------------------------------------------------------------
extern "C" void kernel_launch(void* const* d_in, const int* in_sizes, int n_in,
                              void* d_out, int out_size, void* d_ws, size_t ws_size,
                              hipStream_t stream)
{
    const float* f    = (const float*)d_in[0];
    const float* conc = (const float*)d_in[1];
    const float* wt   = (const float*)d_in[2];
    const float* wp   = (const float*)d_in[3];
    const float* wg   = (const float*)d_in[4];
    const float* wo   = (const float*)d_in[5];
    const float* gsa  = (const float*)d_in[6];
    const float* gmo  = (const float*)d_in[7];
    float* out = (float*)d_out;

    // ws layout (~40.4 MiB):
    //  [0, 32M)   XT bf16 [8][4096][512]; Q/K in place -> later ST + Q2 in place
    //  [32M,36M)  VL bf16 [8][64][4096]  -> later LT (lat transposed)
    //  [36M,40M)  A1/A2 bf16 [8][4096][64] (attention out, n-major)
    //  [40M,...)  WB WO CK CV bf16
    char* ws = (char*)d_ws;
    unsigned short* XT = (unsigned short*)ws;
    unsigned short* VL = (unsigned short*)(ws + ((size_t)32 << 20));
    unsigned short* LT = VL;  // reuse after flash1
    unsigned short* A1 = (unsigned short*)(ws + ((size_t)36 << 20));
    unsigned short* WB = (unsigned short*)(ws + ((size_t)40 << 20));
    unsigned short* WO = WB + 192 * 512;
    unsigned short* CK = WO + 512 * 64;
    unsigned short* CV = CK + 256 * 64;

    dim3 blk256(256), blk128(128);

    precast<<<640, blk256, 0, stream>>>(wt, wp, wg, wo, conc, WB, WO, CK, CV);
    cast_transpose<<<dim3(64, 8, 8), blk256, 0, stream>>>(f, XT);

    // ---- SelfAttention ----
    qkv_gemm<12><<<dim3(64, 8), blk256, 0, stream>>>(XT, WB, VL);
    flash<<<dim3(64, 8), blk128, 0, stream>>>(
        XT, (size_t)HW * CINP,
        XT + 64, CINP, (size_t)HW * CINP,
        VL, HW, (size_t)LCH * HW,
        A1, HW);
    lat_transpose<<<dim3(64, 8), blk256, 0, stream>>>(A1, LT);
    conv_o<<<dim3(64, 8, 8), blk256, 0, stream>>>(LT, WO, f, gsa, out, XT /*emit ST*/);

    // ---- MomentumConceptAttention ----
    qkv_gemm<4><<<dim3(64, 8), blk256, 0, stream>>>(XT /*=ST*/, WB /*wt rows*/, nullptr);
    flash<<<dim3(64, 8), blk128, 0, stream>>>(
        XT, (size_t)HW * CINP,
        CK, LCH, 0,
        CV, 256, 0,
        A1 /*=A2*/, 256);
    lat_transpose<<<dim3(64, 8), blk256, 0, stream>>>(A1, LT);
    conv_o<<<dim3(64, 8, 8), blk256, 0, stream>>>(LT, WO, out, gmo, out, nullptr);
}

// Round 7
// 363.036 us; speedup vs baseline: 1.1016x; 1.1016x over previous
//
#include <hip/hip_runtime.h>
#include <math.h>

#define HW   4096
#define CINP 512
#define LCH  64

typedef short bf8 __attribute__((ext_vector_type(8)));   // 8 bf16 = 4 VGPRs
typedef float f4  __attribute__((ext_vector_type(4)));   // MFMA C/D frag
typedef unsigned int u32x2 __attribute__((ext_vector_type(2)));

__device__ __forceinline__ unsigned short f2bf(float x) {
    union { float f; unsigned int u; } v; v.f = x;
    return (unsigned short)((v.u + 0x7fffu + ((v.u >> 16) & 1u)) >> 16);
}
__device__ __forceinline__ bf8 ldbf8(const unsigned short* p) {
    uint4 u = *(const uint4*)p;
    return __builtin_bit_cast(bf8, u);
}
// pack two f32 -> two bf16 (RNE), dst.lo = a, dst.hi = b
__device__ __forceinline__ unsigned int cvtpk(float a, float b) {
    unsigned int r;
    asm volatile("v_cvt_pk_bf16_f32 %0, %1, %2" : "=v"(r) : "v"(a), "v"(b));
    return r;
}

// -------------------------------------------------------------------------
// precast: weights (+gain) and concepts to bf16, concepts also transposed.
// WB[192][512] = [wt;wp;wg]*gain   WO[512][64]   CK[256][64]   CV[64][256]
// -------------------------------------------------------------------------
__global__ __launch_bounds__(256) void precast(
    const float* __restrict__ wt, const float* __restrict__ wp,
    const float* __restrict__ wg, const float* __restrict__ wo,
    const float* __restrict__ conc,
    unsigned short* __restrict__ WB, unsigned short* __restrict__ WO,
    unsigned short* __restrict__ CK, unsigned short* __restrict__ CV)
{
    const float gain = 0.04419417382415922f;  // 1/sqrt(512)
    int id = blockIdx.x * 256 + threadIdx.x;
    if (id < 98304) {
        int o = id >> 9, k = id & 511;
        const float* w = (o < 64) ? wt : (o < 128) ? wp : wg;
        WB[id] = f2bf(w[(o & 63) * 512 + k] * gain);
    } else if (id < 131072) {
        int j = id - 98304;
        WO[j] = f2bf(wo[j]);
    } else if (id < 147456) {
        int j = id - 131072;
        CK[j] = f2bf(conc[j]);
    } else if (id < 163840) {
        int j = id - 147456;
        int l = j >> 8, m = j & 255;
        CV[j] = f2bf(conc[m * 64 + l]);
    }
}

// -------------------------------------------------------------------------
// cast_transpose: f fp32 [b][512][4096] -> XT bf16 [b][4096][512]
// -------------------------------------------------------------------------
__global__ __launch_bounds__(256) void cast_transpose(const float* __restrict__ x,
                                                      unsigned short* __restrict__ XT)
{
    __shared__ unsigned short Lb[64][72];   // [n][c]
    const int t  = threadIdx.x;
    const int n0 = blockIdx.x * 64, c0 = blockIdx.y * 64, b = blockIdx.z;
    const float* xb = x + ((size_t)b * CINP + c0) * HW + n0;
    const int cc = t >> 4, n4 = (t & 15) * 4;
    #pragma unroll
    for (int i = 0; i < 4; i++) {
        int c = cc + i * 16;
        float4 v = *(const float4*)(xb + (size_t)c * HW + n4);
        Lb[n4 + 0][c] = f2bf(v.x);
        Lb[n4 + 1][c] = f2bf(v.y);
        Lb[n4 + 2][c] = f2bf(v.z);
        Lb[n4 + 3][c] = f2bf(v.w);
    }
    __syncthreads();
    const int n = t & 63, cb0 = t >> 6;
    unsigned short* orow = XT + ((size_t)b * HW + n0 + n) * CINP + c0;
    #pragma unroll
    for (int i = 0; i < 2; i++) {
        int cb = cb0 + i * 4;
        *(uint4*)(orow + cb * 8) = *(const uint4*)&Lb[n][cb * 8];
    }
}

// -------------------------------------------------------------------------
// lat_transpose: A bf16 flat [b][4096][64] viewed as lat[b][64][4096]
// (raw reinterpret, the torch .view) -> LT[b][4096][64] with LT[b][s][c] =
// lat[b][c][s] = Aflat[b*262144 + c*4096 + s].  64x64 LDS tile.
// -------------------------------------------------------------------------
__global__ __launch_bounds__(256) void lat_transpose(const unsigned short* __restrict__ A,
                                                     unsigned short* __restrict__ LT)
{
    __shared__ unsigned short Ls[64][72];
    const int t = threadIdx.x, s0 = blockIdx.x * 64, b = blockIdx.y;
    const unsigned short* ab = A + (size_t)b * LCH * HW;
    #pragma unroll
    for (int it = 0; it < 2; it++) {
        int c = (t >> 3) + it * 32, s8 = (t & 7) * 8;
        union { uint4 u; unsigned short s[8]; } v;
        v.u = *(const uint4*)(ab + (size_t)c * HW + s0 + s8);
        #pragma unroll
        for (int i = 0; i < 8; i++) Ls[s8 + i][c] = v.s[i];
    }
    __syncthreads();
    unsigned short* ob = LT + ((size_t)b * HW + s0) * LCH;
    #pragma unroll
    for (int it = 0; it < 2; it++) {
        int s = (t >> 3) + it * 32, c8 = (t & 7);
        *(uint4*)(ob + (size_t)s * LCH + c8 * 8) = *(const uint4*)&Ls[s][c8 * 8];
    }
}

// -------------------------------------------------------------------------
// qkv_gemm<NRT>: barrier-free, LDS-free; A (weights) and B (XT rows) frags
// direct from global. NRT=12: Q -> XT cols [0,64), K -> [64,128), V -> VL.
// NRT=4: enc -> XT cols [0,64).
// -------------------------------------------------------------------------
template <int NRT>
__global__ __launch_bounds__(256) void qkv_gemm(unsigned short* XT,
                                                const unsigned short* __restrict__ WB,
                                                unsigned short* __restrict__ VL)
{
    const int t = threadIdx.x;
    const int wave = t >> 6, lane = t & 63, quad = lane >> 4, lidx = lane & 15;
    const int b = blockIdx.y;
    const int ncol = blockIdx.x * 64 + wave * 16 + lidx;
    unsigned short* xrow = XT + ((size_t)b * HW + ncol) * CINP;

    f4 acc[NRT];
    #pragma unroll
    for (int r = 0; r < NRT; r++) acc[r] = (f4){0.f, 0.f, 0.f, 0.f};

    for (int kk = 0; kk < 16; kk++) {
        const int k0 = kk * 32 + quad * 8;
        bf8 bq = ldbf8(xrow + k0);
        #pragma unroll
        for (int rt = 0; rt < NRT; rt++) {
            bf8 aw = ldbf8(WB + (size_t)(rt * 16 + lidx) * CINP + k0);
            acc[rt] = __builtin_amdgcn_mfma_f32_16x16x32_bf16(aw, bq, acc[rt], 0, 0, 0);
        }
    }

    #pragma unroll
    for (int rt = 0; rt < NRT; rt++) {
        if (rt < 8) {  // Q (rt<4) and K (rt<8): n-major, in place in XT
            union { unsigned short s[4]; uint2 u; } pk;
            #pragma unroll
            for (int r = 0; r < 4; r++) pk.s[r] = f2bf(acc[rt][r]);
            int off = (rt < 4) ? (rt * 16 + quad * 4) : (64 + (rt - 4) * 16 + quad * 4);
            *(uint2*)(xrow + off) = pk.u;
        } else {       // V: l-major
            #pragma unroll
            for (int r = 0; r < 4; r++) {
                int l = (rt - 8) * 16 + quad * 4 + r;
                VL[((size_t)b * LCH + l) * HW + ncol] = f2bf(acc[rt][r]);
            }
        }
    }
}

// -------------------------------------------------------------------------
// flash: split-Q, cooperative-LDS-staging, max-free-softmax MFMA attention.
// Block = 8 waves x 16 queries = 128 queries (512 threads); grid 32x8 = 256
// blocks = 1 block/CU, 2 waves/SIMD.
//
// KVBLK = 64 (was 32): rounds 1-6 showed time/iteration ~2100 cy regardless
// of waves, DS volume, and cache residency, vs ~800 cy of accounted work ->
// a FIXED per-iteration cost (prefetch vmcnt drain + barrier + ds_read/MFMA
// start chain) dominates. Doubling the tile halves the iteration (=barrier)
// count and makes per-iteration compute (~1200 cy) exceed the prefetch
// latency (~650 cy), hiding the depth-1 vmcnt stall entirely.
//
// P never touches LDS (round-6, proven): after swapped QK^T
// (S = mfma(K,Q) -> D[key][query]), P is repacked to the PV A-operand
// layout in registers via v_cvt_pk_bf16_f32 + permlane32/16_swap builtins.
// Out: bf16 [b][4096][64] (n-major).
// -------------------------------------------------------------------------
__global__ __launch_bounds__(512) void flash(
    const unsigned short* Qb, size_t qbat,
    const unsigned short* Kb, size_t krow, size_t kbat,
    const unsigned short* Vb, size_t vrow, size_t vbat,
    unsigned short* __restrict__ Aout, int nkeys)
{
    __shared__ __align__(16) unsigned short Ks[2][64][72];     // [buf][key][ch]
    __shared__ __align__(16) unsigned short Vs[2][2][64][40];  // [buf][kseg][l][key]

    const int t = threadIdx.x;          // 0..511
    const int wave = t >> 6, lane = t & 63, quad = lane >> 4, lidx = lane & 15;
    const int b = blockIdx.y, q0 = blockIdx.x * 128 + wave * 16;

    const unsigned short* qp = Qb + (size_t)b * qbat;
    const unsigned short* kp = Kb + (size_t)b * kbat;
    const unsigned short* vp = Vb + (size_t)b * vbat;

    // staging: 1 K chunk + 1 V chunk (16B each) per thread per tile
    const int srow = t >> 3, sch = t & 7;            // K: key srow, chunk sch
    const int vseg = sch >> 2, vcs = sch & 3;        // V: l srow, key-seg/chunk
    const unsigned short* ksrc = kp + (size_t)srow * krow + sch * 8;
    const unsigned short* vsrc = vp + (size_t)srow * vrow + sch * 8;
    const size_t kstep = (size_t)64 * krow;          // advance 64 keys

    // Q fragments (B-operand of swapped QK): Q[query lidx][ch kh*32+quad*8]
    bf8 qa[2];
    #pragma unroll
    for (int kh = 0; kh < 2; kh++)
        qa[kh] = ldbf8(qp + (size_t)(q0 + lidx) * CINP + kh * 32 + quad * 8);

    f4 O[4];
    float Lp = 0.f;
    #pragma unroll
    for (int lt = 0; lt < 4; lt++) O[lt] = (f4){0.f, 0.f, 0.f, 0.f};

    const int nt = nkeys >> 6;

    // prologue: stage tile 0 into buf 0
    *(uint4*)&Ks[0][srow][sch * 8]       = *(const uint4*)ksrc;
    *(uint4*)&Vs[0][vseg][srow][vcs * 8] = *(const uint4*)vsrc;
    ksrc += kstep; vsrc += 64;
    __syncthreads();

    for (int tl = 0; tl < nt; tl++) {
        const int cur = tl & 1;
        const bool pfv = (tl + 1 < nt);
        uint4 kq, vq;
        if (pfv) {  // issue next-tile global loads early; written after compute
            kq = *(const uint4*)ksrc;
            vq = *(const uint4*)vsrc;
            ksrc += kstep; vsrc += 64;
        }

        // K frags (A-operand): K[key ms*16+lidx][ch kh*32+quad*8]
        bf8 kf[4][2];
        #pragma unroll
        for (int ms = 0; ms < 4; ms++)
            #pragma unroll
            for (int kh = 0; kh < 2; kh++)
                kf[ms][kh] = *(const bf8*)&Ks[cur][ms * 16 + lidx][kh * 32 + quad * 8];

        // S = K . Q^T : D[key quad*4+r (+ms*16)][query lidx]
        f4 S[4];
        #pragma unroll
        for (int ms = 0; ms < 4; ms++) {
            f4 s = (f4){0.f, 0.f, 0.f, 0.f};
            s = __builtin_amdgcn_mfma_f32_16x16x32_bf16(kf[ms][0], qa[0], s, 0, 0, 0);
            s = __builtin_amdgcn_mfma_f32_16x16x32_bf16(kf[ms][1], qa[1], s, 0, 0, 0);
            S[ms] = s;
        }

        // P = exp(S); repack D[key][query] -> A-operand P[query][key] in regs
        // (keys bounded: scores ~|50| max-free exp is safe in fp32)
        bf8 pa[2];
        #pragma unroll
        for (int p = 0; p < 2; p++) {
            float e00 = __expf(S[2 * p][0]),     e01 = __expf(S[2 * p][1]);
            float e02 = __expf(S[2 * p][2]),     e03 = __expf(S[2 * p][3]);
            float e10 = __expf(S[2 * p + 1][0]), e11 = __expf(S[2 * p + 1][1]);
            float e12 = __expf(S[2 * p + 1][2]), e13 = __expf(S[2 * p + 1][3]);
            Lp += ((e00 + e01) + (e02 + e03)) + ((e10 + e11) + (e12 + e13));
            unsigned int A = cvtpk(e00, e01), B = cvtpk(e02, e03);
            unsigned int C = cvtpk(e10, e11), D = cvtpk(e12, e13);
            u32x2 ac = __builtin_amdgcn_permlane32_swap(A, C, false, false);
            u32x2 xz = __builtin_amdgcn_permlane16_swap(ac.x, ac.y, false, false);
            u32x2 bd = __builtin_amdgcn_permlane32_swap(B, D, false, false);
            u32x2 yw = __builtin_amdgcn_permlane16_swap(bd.x, bd.y, false, false);
            uint4 pu; pu.x = xz.x; pu.y = yw.x; pu.z = xz.y; pu.w = yw.y;
            pa[p] = __builtin_bit_cast(bf8, pu);
        }

        // PV: A = P[query][key-seg g], B = V[l][key-seg g]; accumulate over g
        #pragma unroll
        for (int g = 0; g < 2; g++)
            #pragma unroll
            for (int lt = 0; lt < 4; lt++) {
                bf8 vf = *(const bf8*)&Vs[cur][g][lt * 16 + lidx][quad * 8];
                O[lt] = __builtin_amdgcn_mfma_f32_16x16x32_bf16(pa[g], vf, O[lt], 0, 0, 0);
            }

        if (pfv) {  // write prefetched tile into the other buffer
            *(uint4*)&Ks[cur ^ 1][srow][sch * 8]       = kq;
            *(uint4*)&Vs[cur ^ 1][vseg][srow][vcs * 8] = vq;
        }
        __syncthreads();
    }

    // ---- normalize & write: L[query] lives at lane lidx=query (cross-quad sum) ----
    float s = Lp;
    s += __shfl_xor(s, 16);
    s += __shfl_xor(s, 32);
    const float inv = 1.f / s;
    #pragma unroll
    for (int r = 0; r < 4; r++) {
        float iv = __shfl(inv, quad * 4 + r);  // query quad*4+r
        size_t n = (size_t)b * HW + q0 + quad * 4 + r;
        #pragma unroll
        for (int lt = 0; lt < 4; lt++)
            Aout[n * LCH + lt * 16 + lidx] = f2bf(O[lt][r] * iv);
    }
}

// -------------------------------------------------------------------------
// conv_o: out[b,o,s] = gamma/8 * sum_c WO[o,c]*LT[s,c] + res[b,o,s]
// LT: bf16 [b][4096][64] with LT[s][c] = lat[c][s] (lat_transpose output).
// Optionally emits ST bf16 [b][s][512] (transposed sa_out for stage-2).
// -------------------------------------------------------------------------
__global__ __launch_bounds__(256) void conv_o(const unsigned short* __restrict__ LT,
                                              const unsigned short* __restrict__ WO,
                                              const float* __restrict__ res,
                                              const float* __restrict__ gamma_p,
                                              float* __restrict__ out,
                                              unsigned short* ST)
{
    const int t = threadIdx.x;
    const int wave = t >> 6, lane = t & 63, quad = lane >> 4, lidx = lane & 15;
    const int b = blockIdx.z, o0 = blockIdx.y * 64;
    const int scol = blockIdx.x * 64 + wave * 16 + lidx;
    const unsigned short* arow = LT + ((size_t)b * HW + scol) * LCH;

    f4 acc[4];
    #pragma unroll
    for (int ot = 0; ot < 4; ot++) acc[ot] = (f4){0.f, 0.f, 0.f, 0.f};

    #pragma unroll
    for (int kh = 0; kh < 2; kh++) {
        bf8 bq = ldbf8(arow + kh * 32 + quad * 8);
        #pragma unroll
        for (int ot = 0; ot < 4; ot++) {
            bf8 af = ldbf8(WO + (size_t)(o0 + ot * 16 + lidx) * LCH + kh * 32 + quad * 8);
            acc[ot] = __builtin_amdgcn_mfma_f32_16x16x32_bf16(af, bq, acc[ot], 0, 0, 0);
        }
    }

    const float scale = gamma_p[0] * 0.125f;  // gamma * 1/sqrt(64)
    #pragma unroll
    for (int ot = 0; ot < 4; ot++) {
        float v[4];
        #pragma unroll
        for (int r = 0; r < 4; r++) {
            size_t idx = ((size_t)b * CINP + o0 + ot * 16 + quad * 4 + r) * HW + scol;
            v[r] = fmaf(scale, acc[ot][r], res[idx]);
            out[idx] = v[r];
        }
        if (ST) {
            union { unsigned short s[4]; uint2 u; } pk;
            #pragma unroll
            for (int r = 0; r < 4; r++) pk.s[r] = f2bf(v[r]);
            *(uint2*)(ST + ((size_t)b * HW + scol) * CINP + o0 + ot * 16 + quad * 4) = pk.u;
        }
    }
}

// -------------------------------------------------------------------------
extern "C" void kernel_launch(void* const* d_in, const int* in_sizes, int n_in,
                              void* d_out, int out_size, void* d_ws, size_t ws_size,
                              hipStream_t stream)
{
    const float* f    = (const float*)d_in[0];
    const float* conc = (const float*)d_in[1];
    const float* wt   = (const float*)d_in[2];
    const float* wp   = (const float*)d_in[3];
    const float* wg   = (const float*)d_in[4];
    const float* wo   = (const float*)d_in[5];
    const float* gsa  = (const float*)d_in[6];
    const float* gmo  = (const float*)d_in[7];
    float* out = (float*)d_out;

    // ws layout (~40.4 MiB):
    //  [0, 32M)   XT bf16 [8][4096][512]; Q/K in place -> later ST + Q2 in place
    //  [32M,36M)  VL bf16 [8][64][4096]  -> later LT (lat transposed)
    //  [36M,40M)  A1/A2 bf16 [8][4096][64] (attention out, n-major)
    //  [40M,...)  WB WO CK CV bf16
    char* ws = (char*)d_ws;
    unsigned short* XT = (unsigned short*)ws;
    unsigned short* VL = (unsigned short*)(ws + ((size_t)32 << 20));
    unsigned short* LT = VL;  // reuse after flash1
    unsigned short* A1 = (unsigned short*)(ws + ((size_t)36 << 20));
    unsigned short* WB = (unsigned short*)(ws + ((size_t)40 << 20));
    unsigned short* WO = WB + 192 * 512;
    unsigned short* CK = WO + 512 * 64;
    unsigned short* CV = CK + 256 * 64;

    dim3 blk256(256), blk512(512);

    precast<<<640, blk256, 0, stream>>>(wt, wp, wg, wo, conc, WB, WO, CK, CV);
    cast_transpose<<<dim3(64, 8, 8), blk256, 0, stream>>>(f, XT);

    // ---- SelfAttention ----
    qkv_gemm<12><<<dim3(64, 8), blk256, 0, stream>>>(XT, WB, VL);
    flash<<<dim3(32, 8), blk512, 0, stream>>>(
        XT, (size_t)HW * CINP,
        XT + 64, CINP, (size_t)HW * CINP,
        VL, HW, (size_t)LCH * HW,
        A1, HW);
    lat_transpose<<<dim3(64, 8), blk256, 0, stream>>>(A1, LT);
    conv_o<<<dim3(64, 8, 8), blk256, 0, stream>>>(LT, WO, f, gsa, out, XT /*emit ST*/);

    // ---- MomentumConceptAttention ----
    qkv_gemm<4><<<dim3(64, 8), blk256, 0, stream>>>(XT /*=ST*/, WB /*wt rows*/, nullptr);
    flash<<<dim3(32, 8), blk512, 0, stream>>>(
        XT, (size_t)HW * CINP,
        CK, LCH, 0,
        CV, 256, 0,
        A1 /*=A2*/, 256);
    lat_transpose<<<dim3(64, 8), blk256, 0, stream>>>(A1, LT);
    conv_o<<<dim3(64, 8, 8), blk256, 0, stream>>>(LT, WO, out, gmo, out, nullptr);
}

// Round 9
// 356.776 us; speedup vs baseline: 1.1209x; 1.0175x over previous
//
#include <hip/hip_runtime.h>
#include <math.h>

#define HW   4096
#define CINP 512
#define LCH  64

typedef short bf8 __attribute__((ext_vector_type(8)));   // 8 bf16 = 4 VGPRs
typedef float f4  __attribute__((ext_vector_type(4)));   // MFMA C/D frag
typedef unsigned int u32x2 __attribute__((ext_vector_type(2)));

__device__ __forceinline__ unsigned short f2bf(float x) {
    union { float f; unsigned int u; } v; v.f = x;
    return (unsigned short)((v.u + 0x7fffu + ((v.u >> 16) & 1u)) >> 16);
}
__device__ __forceinline__ bf8 ldbf8(const unsigned short* p) {
    uint4 u = *(const uint4*)p;
    return __builtin_bit_cast(bf8, u);
}
// pack two f32 -> two bf16 (RNE), dst.lo = a, dst.hi = b
__device__ __forceinline__ unsigned int cvtpk(float a, float b) {
    unsigned int r;
    asm volatile("v_cvt_pk_bf16_f32 %0, %1, %2" : "=v"(r) : "v"(a), "v"(b));
    return r;
}

// -------------------------------------------------------------------------
// precast: weights (+gain) and concepts to bf16, concepts also transposed.
// WB[192][512] = [wt;wp;wg]*gain   WO[512][64]   CK[256][64]   CV[64][256]
// -------------------------------------------------------------------------
__global__ __launch_bounds__(256) void precast(
    const float* __restrict__ wt, const float* __restrict__ wp,
    const float* __restrict__ wg, const float* __restrict__ wo,
    const float* __restrict__ conc,
    unsigned short* __restrict__ WB, unsigned short* __restrict__ WO,
    unsigned short* __restrict__ CK, unsigned short* __restrict__ CV)
{
    const float gain = 0.04419417382415922f;  // 1/sqrt(512)
    int id = blockIdx.x * 256 + threadIdx.x;
    if (id < 98304) {
        int o = id >> 9, k = id & 511;
        const float* w = (o < 64) ? wt : (o < 128) ? wp : wg;
        WB[id] = f2bf(w[(o & 63) * 512 + k] * gain);
    } else if (id < 131072) {
        int j = id - 98304;
        WO[j] = f2bf(wo[j]);
    } else if (id < 147456) {
        int j = id - 131072;
        CK[j] = f2bf(conc[j]);
    } else if (id < 163840) {
        int j = id - 147456;
        int l = j >> 8, m = j & 255;
        CV[j] = f2bf(conc[m * 64 + l]);
    }
}

// -------------------------------------------------------------------------
// cast_transpose: f fp32 [b][512][4096] -> XT bf16 [b][4096][512]
// -------------------------------------------------------------------------
__global__ __launch_bounds__(256) void cast_transpose(const float* __restrict__ x,
                                                      unsigned short* __restrict__ XT)
{
    __shared__ unsigned short Lb[64][72];   // [n][c]
    const int t  = threadIdx.x;
    const int n0 = blockIdx.x * 64, c0 = blockIdx.y * 64, b = blockIdx.z;
    const float* xb = x + ((size_t)b * CINP + c0) * HW + n0;
    const int cc = t >> 4, n4 = (t & 15) * 4;
    #pragma unroll
    for (int i = 0; i < 4; i++) {
        int c = cc + i * 16;
        float4 v = *(const float4*)(xb + (size_t)c * HW + n4);
        Lb[n4 + 0][c] = f2bf(v.x);
        Lb[n4 + 1][c] = f2bf(v.y);
        Lb[n4 + 2][c] = f2bf(v.z);
        Lb[n4 + 3][c] = f2bf(v.w);
    }
    __syncthreads();
    const int n = t & 63, cb0 = t >> 6;
    unsigned short* orow = XT + ((size_t)b * HW + n0 + n) * CINP + c0;
    #pragma unroll
    for (int i = 0; i < 2; i++) {
        int cb = cb0 + i * 4;
        *(uint4*)(orow + cb * 8) = *(const uint4*)&Lb[n][cb * 8];
    }
}

// -------------------------------------------------------------------------
// lat_transpose: A bf16 flat [b][4096][64] viewed as lat[b][64][4096]
// (raw reinterpret, the torch .view) -> LT[b][4096][64] with LT[b][s][c] =
// lat[b][c][s] = Aflat[b*262144 + c*4096 + s].  64x64 LDS tile.
// -------------------------------------------------------------------------
__global__ __launch_bounds__(256) void lat_transpose(const unsigned short* __restrict__ A,
                                                     unsigned short* __restrict__ LT)
{
    __shared__ unsigned short Ls[64][72];
    const int t = threadIdx.x, s0 = blockIdx.x * 64, b = blockIdx.y;
    const unsigned short* ab = A + (size_t)b * LCH * HW;
    #pragma unroll
    for (int it = 0; it < 2; it++) {
        int c = (t >> 3) + it * 32, s8 = (t & 7) * 8;
        union { uint4 u; unsigned short s[8]; } v;
        v.u = *(const uint4*)(ab + (size_t)c * HW + s0 + s8);
        #pragma unroll
        for (int i = 0; i < 8; i++) Ls[s8 + i][c] = v.s[i];
    }
    __syncthreads();
    unsigned short* ob = LT + ((size_t)b * HW + s0) * LCH;
    #pragma unroll
    for (int it = 0; it < 2; it++) {
        int s = (t >> 3) + it * 32, c8 = (t & 7);
        *(uint4*)(ob + (size_t)s * LCH + c8 * 8) = *(const uint4*)&Ls[s][c8 * 8];
    }
}

// -------------------------------------------------------------------------
// qkv_gemm<NRT>: barrier-free, LDS-free; A (weights) and B (XT rows) frags
// direct from global. NRT=12: Q -> XT cols [0,64), K -> [64,128), V -> VL.
// NRT=4: enc -> XT cols [0,64).
// -------------------------------------------------------------------------
template <int NRT>
__global__ __launch_bounds__(256) void qkv_gemm(unsigned short* XT,
                                                const unsigned short* __restrict__ WB,
                                                unsigned short* __restrict__ VL)
{
    const int t = threadIdx.x;
    const int wave = t >> 6, lane = t & 63, quad = lane >> 4, lidx = lane & 15;
    const int b = blockIdx.y;
    const int ncol = blockIdx.x * 64 + wave * 16 + lidx;
    unsigned short* xrow = XT + ((size_t)b * HW + ncol) * CINP;

    f4 acc[NRT];
    #pragma unroll
    for (int r = 0; r < NRT; r++) acc[r] = (f4){0.f, 0.f, 0.f, 0.f};

    for (int kk = 0; kk < 16; kk++) {
        const int k0 = kk * 32 + quad * 8;
        bf8 bq = ldbf8(xrow + k0);
        #pragma unroll
        for (int rt = 0; rt < NRT; rt++) {
            bf8 aw = ldbf8(WB + (size_t)(rt * 16 + lidx) * CINP + k0);
            acc[rt] = __builtin_amdgcn_mfma_f32_16x16x32_bf16(aw, bq, acc[rt], 0, 0, 0);
        }
    }

    #pragma unroll
    for (int rt = 0; rt < NRT; rt++) {
        if (rt < 8) {  // Q (rt<4) and K (rt<8): n-major, in place in XT
            union { unsigned short s[4]; uint2 u; } pk;
            #pragma unroll
            for (int r = 0; r < 4; r++) pk.s[r] = f2bf(acc[rt][r]);
            int off = (rt < 4) ? (rt * 16 + quad * 4) : (64 + (rt - 4) * 16 + quad * 4);
            *(uint2*)(xrow + off) = pk.u;
        } else {       // V: l-major
            #pragma unroll
            for (int r = 0; r < 4; r++) {
                int l = (rt - 8) * 16 + quad * 4 + r;
                VL[((size_t)b * LCH + l) * HW + ncol] = f2bf(acc[rt][r]);
            }
        }
    }
}

// -------------------------------------------------------------------------
// flash: split-Q x split-K wave-specialized, LDS-staged, max-free-softmax
// MFMA attention. Block = 8 waves (512 thr) = 4 query-groups x 2 key-halves:
// wave (qh, g) handles 32 queries x the 32-key half g of each 64-key tile.
// Per-wave DS reads HALVE vs round 7 (4 K-frag + 4 V-frag b128 per iter) --
// round-7 counters showed DS-read pipe = ~2300 of 2712 cy/iter. Max-free
// softmax makes the key-split partials (O, Lp) LINEAR: one LDS combine after
// the loop, amortized over all iterations.
//
// LDS: ONE flat char array; Ks/Vs/Red all derived via in-bounds char*
// arithmetic. (Round 8 derived the combine buffer from &Ks[0][0][0] --
// out-of-bounds pointer arithmetic on the Ks object, UB the optimizer
// exploited -> dropped stores -> stale bf16 K-bits read as f32 NaNs.)
//
// P never touches LDS (round-6, proven): after swapped QK^T
// (S = mfma(K,Q) -> D[key][query]), P is repacked to the PV A-operand
// layout in registers via v_cvt_pk_bf16_f32 + permlane32/16_swap builtins.
// Out: bf16 [b][4096][64] (n-major).
// -------------------------------------------------------------------------
__global__ __launch_bounds__(512) void flash(
    const unsigned short* Qb, size_t qbat,
    const unsigned short* Kb, size_t krow, size_t kbat,
    const unsigned short* Vb, size_t vrow, size_t vbat,
    unsigned short* __restrict__ Aout, int nkeys)
{
    // layout: [0,18432) Ks[2][64][72]  |  [18432,38912) Vs[2][2][64][40]
    // Red (combine, after loop): [0,35840) as float[4][64][35] slots
    __shared__ __align__(16) char smem[38912];
    unsigned short (*Ks)[64][72]     = (unsigned short (*)[64][72])smem;
    unsigned short (*Vs)[2][64][40]  = (unsigned short (*)[2][64][40])(smem + 18432);
    float* Red = (float*)smem;

    const int t = threadIdx.x;          // 0..511
    const int wave = t >> 6, lane = t & 63, quad = lane >> 4, lidx = lane & 15;
    const int qh = wave & 3, g = wave >> 2;
    const int b = blockIdx.y, q0 = blockIdx.x * 128 + qh * 32;

    const unsigned short* qp = Qb + (size_t)b * qbat;
    const unsigned short* kp = Kb + (size_t)b * kbat;
    const unsigned short* vp = Vb + (size_t)b * vbat;

    // staging: 1 K chunk + 1 V chunk (16B each) per thread per tile
    const int srow = t >> 3, sch = t & 7;            // K: key srow, chunk sch
    const int vseg = sch >> 2, vcs = sch & 3;        // V: l srow, key-seg/chunk
    const unsigned short* ksrc = kp + (size_t)srow * krow + sch * 8;
    const unsigned short* vsrc = vp + (size_t)srow * vrow + sch * 8;
    const size_t kstep = (size_t)64 * krow;          // advance 64 keys

    // Q fragments (B-operand of swapped QK): Q[query qb*16+lidx][ch kh*32+quad*8]
    bf8 qa[2][2];
    #pragma unroll
    for (int qb = 0; qb < 2; qb++)
        #pragma unroll
        for (int kh = 0; kh < 2; kh++)
            qa[qb][kh] = ldbf8(qp + (size_t)(q0 + qb * 16 + lidx) * CINP + kh * 32 + quad * 8);

    f4 O[2][4];
    float Lp[2] = {0.f, 0.f};
    #pragma unroll
    for (int qb = 0; qb < 2; qb++)
        #pragma unroll
        for (int lt = 0; lt < 4; lt++) O[qb][lt] = (f4){0.f, 0.f, 0.f, 0.f};

    const int nt = nkeys >> 6;

    // prologue: stage tile 0 into buf 0
    *(uint4*)&Ks[0][srow][sch * 8]       = *(const uint4*)ksrc;
    *(uint4*)&Vs[0][vseg][srow][vcs * 8] = *(const uint4*)vsrc;
    ksrc += kstep; vsrc += 64;
    __syncthreads();

    for (int tl = 0; tl < nt; tl++) {
        const int cur = tl & 1;
        const bool pfv = (tl + 1 < nt);
        uint4 kq, vq;
        if (pfv) {  // issue next-tile global loads early; written after compute
            kq = *(const uint4*)ksrc;
            vq = *(const uint4*)vsrc;
            ksrc += kstep; vsrc += 64;
        }

        // K frags (A-operand), this wave's key half g:
        // K[key g*32+ms*16+lidx][ch kh*32+quad*8]
        bf8 kf[2][2];
        #pragma unroll
        for (int ms = 0; ms < 2; ms++)
            #pragma unroll
            for (int kh = 0; kh < 2; kh++)
                kf[ms][kh] = *(const bf8*)&Ks[cur][g * 32 + ms * 16 + lidx][kh * 32 + quad * 8];

        // S = K . Q^T : D[key g*32+ms*16+quad*4+r][query q0+qb*16+lidx]
        f4 S[2][2];
        #pragma unroll
        for (int qb = 0; qb < 2; qb++)
            #pragma unroll
            for (int ms = 0; ms < 2; ms++) {
                f4 s = (f4){0.f, 0.f, 0.f, 0.f};
                s = __builtin_amdgcn_mfma_f32_16x16x32_bf16(kf[ms][0], qa[qb][0], s, 0, 0, 0);
                s = __builtin_amdgcn_mfma_f32_16x16x32_bf16(kf[ms][1], qa[qb][1], s, 0, 0, 0);
                S[qb][ms] = s;
            }

        // P = exp(S); repack D[key][query] -> A-operand P[query][key] in regs
        bf8 pa[2];
        #pragma unroll
        for (int qb = 0; qb < 2; qb++) {
            float e00 = __expf(S[qb][0][0]), e01 = __expf(S[qb][0][1]);
            float e02 = __expf(S[qb][0][2]), e03 = __expf(S[qb][0][3]);
            float e10 = __expf(S[qb][1][0]), e11 = __expf(S[qb][1][1]);
            float e12 = __expf(S[qb][1][2]), e13 = __expf(S[qb][1][3]);
            Lp[qb] += ((e00 + e01) + (e02 + e03)) + ((e10 + e11) + (e12 + e13));
            unsigned int A = cvtpk(e00, e01), B = cvtpk(e02, e03);
            unsigned int C = cvtpk(e10, e11), D = cvtpk(e12, e13);
            u32x2 ac = __builtin_amdgcn_permlane32_swap(A, C, false, false);
            u32x2 xz = __builtin_amdgcn_permlane16_swap(ac.x, ac.y, false, false);
            u32x2 bd = __builtin_amdgcn_permlane32_swap(B, D, false, false);
            u32x2 yw = __builtin_amdgcn_permlane16_swap(bd.x, bd.y, false, false);
            uint4 pu; pu.x = xz.x; pu.y = yw.x; pu.z = xz.y; pu.w = yw.y;
            pa[qb] = __builtin_bit_cast(bf8, pu);
        }

        // PV over this wave's key half: A = P[query][key], B = V[l][key]
        #pragma unroll
        for (int lt = 0; lt < 4; lt++) {
            bf8 vf = *(const bf8*)&Vs[cur][g][lt * 16 + lidx][quad * 8];
            O[0][lt] = __builtin_amdgcn_mfma_f32_16x16x32_bf16(pa[0], vf, O[0][lt], 0, 0, 0);
            O[1][lt] = __builtin_amdgcn_mfma_f32_16x16x32_bf16(pa[1], vf, O[1][lt], 0, 0, 0);
        }

        if (pfv) {  // write prefetched tile into the other buffer
            *(uint4*)&Ks[cur ^ 1][srow][sch * 8]       = kq;
            *(uint4*)&Vs[cur ^ 1][vseg][srow][vcs * 8] = vq;
        }
        __syncthreads();
    }

    // ---- cross-wave key-half combine: O, Lp are linear partial sums ----
    // Red = float slots [qh*64+lane][35]; stride 35 (odd) -> conflict-free.
    if (g == 1) {
        float* rp = Red + (size_t)(qh * 64 + lane) * 35;
        int j = 0;
        #pragma unroll
        for (int qb = 0; qb < 2; qb++)
            #pragma unroll
            for (int lt = 0; lt < 4; lt++)
                #pragma unroll
                for (int r = 0; r < 4; r++) rp[j++] = O[qb][lt][r];
        rp[32] = Lp[0];
        rp[33] = Lp[1];
    }
    __syncthreads();
    if (g == 0) {
        const float* rp = Red + (size_t)(qh * 64 + lane) * 35;
        int j = 0;
        #pragma unroll
        for (int qb = 0; qb < 2; qb++)
            #pragma unroll
            for (int lt = 0; lt < 4; lt++)
                #pragma unroll
                for (int r = 0; r < 4; r++) O[qb][lt][r] += rp[j++];
        Lp[0] += rp[32];
        Lp[1] += rp[33];

        // normalize & write: L[query] lives at lane lidx=query (cross-quad sum)
        float inv[2];
        #pragma unroll
        for (int qb = 0; qb < 2; qb++) {
            float s = Lp[qb];
            s += __shfl_xor(s, 16);
            s += __shfl_xor(s, 32);
            inv[qb] = 1.f / s;
        }
        #pragma unroll
        for (int qb = 0; qb < 2; qb++)
            #pragma unroll
            for (int r = 0; r < 4; r++) {
                float iv = __shfl(inv[qb], quad * 4 + r);  // query qb*16+quad*4+r
                size_t n = (size_t)b * HW + q0 + qb * 16 + quad * 4 + r;
                #pragma unroll
                for (int lt = 0; lt < 4; lt++)
                    Aout[n * LCH + lt * 16 + lidx] = f2bf(O[qb][lt][r] * iv);
            }
    }
}

// -------------------------------------------------------------------------
// conv_o: out[b,o,s] = gamma/8 * sum_c WO[o,c]*LT[s,c] + res[b,o,s]
// LT: bf16 [b][4096][64] with LT[s][c] = lat[c][s] (lat_transpose output).
// Optionally emits ST bf16 [b][s][512] (transposed sa_out for stage-2).
// -------------------------------------------------------------------------
__global__ __launch_bounds__(256) void conv_o(const unsigned short* __restrict__ LT,
                                              const unsigned short* __restrict__ WO,
                                              const float* __restrict__ res,
                                              const float* __restrict__ gamma_p,
                                              float* __restrict__ out,
                                              unsigned short* ST)
{
    const int t = threadIdx.x;
    const int wave = t >> 6, lane = t & 63, quad = lane >> 4, lidx = lane & 15;
    const int b = blockIdx.z, o0 = blockIdx.y * 64;
    const int scol = blockIdx.x * 64 + wave * 16 + lidx;
    const unsigned short* arow = LT + ((size_t)b * HW + scol) * LCH;

    f4 acc[4];
    #pragma unroll
    for (int ot = 0; ot < 4; ot++) acc[ot] = (f4){0.f, 0.f, 0.f, 0.f};

    #pragma unroll
    for (int kh = 0; kh < 2; kh++) {
        bf8 bq = ldbf8(arow + kh * 32 + quad * 8);
        #pragma unroll
        for (int ot = 0; ot < 4; ot++) {
            bf8 af = ldbf8(WO + (size_t)(o0 + ot * 16 + lidx) * LCH + kh * 32 + quad * 8);
            acc[ot] = __builtin_amdgcn_mfma_f32_16x16x32_bf16(af, bq, acc[ot], 0, 0, 0);
        }
    }

    const float scale = gamma_p[0] * 0.125f;  // gamma * 1/sqrt(64)
    #pragma unroll
    for (int ot = 0; ot < 4; ot++) {
        float v[4];
        #pragma unroll
        for (int r = 0; r < 4; r++) {
            size_t idx = ((size_t)b * CINP + o0 + ot * 16 + quad * 4 + r) * HW + scol;
            v[r] = fmaf(scale, acc[ot][r], res[idx]);
            out[idx] = v[r];
        }
        if (ST) {
            union { unsigned short s[4]; uint2 u; } pk;
            #pragma unroll
            for (int r = 0; r < 4; r++) pk.s[r] = f2bf(v[r]);
            *(uint2*)(ST + ((size_t)b * HW + scol) * CINP + o0 + ot * 16 + quad * 4) = pk.u;
        }
    }
}

// -------------------------------------------------------------------------
extern "C" void kernel_launch(void* const* d_in, const int* in_sizes, int n_in,
                              void* d_out, int out_size, void* d_ws, size_t ws_size,
                              hipStream_t stream)
{
    const float* f    = (const float*)d_in[0];
    const float* conc = (const float*)d_in[1];
    const float* wt   = (const float*)d_in[2];
    const float* wp   = (const float*)d_in[3];
    const float* wg   = (const float*)d_in[4];
    const float* wo   = (const float*)d_in[5];
    const float* gsa  = (const float*)d_in[6];
    const float* gmo  = (const float*)d_in[7];
    float* out = (float*)d_out;

    // ws layout (~40.4 MiB):
    //  [0, 32M)   XT bf16 [8][4096][512]; Q/K in place -> later ST + Q2 in place
    //  [32M,36M)  VL bf16 [8][64][4096]  -> later LT (lat transposed)
    //  [36M,40M)  A1/A2 bf16 [8][4096][64] (attention out, n-major)
    //  [40M,...)  WB WO CK CV bf16
    char* ws = (char*)d_ws;
    unsigned short* XT = (unsigned short*)ws;
    unsigned short* VL = (unsigned short*)(ws + ((size_t)32 << 20));
    unsigned short* LT = VL;  // reuse after flash1
    unsigned short* A1 = (unsigned short*)(ws + ((size_t)36 << 20));
    unsigned short* WB = (unsigned short*)(ws + ((size_t)40 << 20));
    unsigned short* WO = WB + 192 * 512;
    unsigned short* CK = WO + 512 * 64;
    unsigned short* CV = CK + 256 * 64;

    dim3 blk256(256), blk512(512);

    precast<<<640, blk256, 0, stream>>>(wt, wp, wg, wo, conc, WB, WO, CK, CV);
    cast_transpose<<<dim3(64, 8, 8), blk256, 0, stream>>>(f, XT);

    // ---- SelfAttention ----
    qkv_gemm<12><<<dim3(64, 8), blk256, 0, stream>>>(XT, WB, VL);
    flash<<<dim3(32, 8), blk512, 0, stream>>>(
        XT, (size_t)HW * CINP,
        XT + 64, CINP, (size_t)HW * CINP,
        VL, HW, (size_t)LCH * HW,
        A1, HW);
    lat_transpose<<<dim3(64, 8), blk256, 0, stream>>>(A1, LT);
    conv_o<<<dim3(64, 8, 8), blk256, 0, stream>>>(LT, WO, f, gsa, out, XT /*emit ST*/);

    // ---- MomentumConceptAttention ----
    qkv_gemm<4><<<dim3(64, 8), blk256, 0, stream>>>(XT /*=ST*/, WB /*wt rows*/, nullptr);
    flash<<<dim3(32, 8), blk512, 0, stream>>>(
        XT, (size_t)HW * CINP,
        CK, LCH, 0,
        CV, 256, 0,
        A1 /*=A2*/, 256);
    lat_transpose<<<dim3(64, 8), blk256, 0, stream>>>(A1, LT);
    conv_o<<<dim3(64, 8, 8), blk256, 0, stream>>>(LT, WO, out, gmo, out, nullptr);
}